// Round 23
// baseline (147.924 us; speedup 1.0000x reference)
//
#include <hip/hip_runtime.h>
#include <hip/hip_bf16.h>
#include <cstdint>
#include <cstddef>

#define DIM   1024
#define NH    16
#define HD    64
#define BB    4
#define TT    2048

typedef __attribute__((ext_vector_type(8))) short bf16x8;
typedef __attribute__((ext_vector_type(4))) short bf16x4;
typedef __attribute__((ext_vector_type(4))) float f32x4;
typedef __attribute__((ext_vector_type(4))) unsigned short u16x4;
typedef unsigned short u16;
typedef unsigned int u32;

#define NEG_INF (-__builtin_inff())
#define QSCALE 0.18033688011110543f  // 0.125 * log2(e): softmax becomes exp2
#define AS1 __attribute__((address_space(1)))
#define AS3 __attribute__((address_space(3)))

static __device__ __forceinline__ u16 f2bf(float f) {
  union { float f; unsigned u; } v; v.f = f;
  return (u16)((v.u + 0x7FFFu + ((v.u >> 16) & 1u)) >> 16);
}

static __device__ __forceinline__ u16 bfbits(float a) {
  union { __hip_bfloat16 h; u16 u; } c; c.h = __float2bfloat16(a); return c.u;
}
static __device__ __forceinline__ u32 pk_bf16(float a, float b) {
  return (u32)bfbits(a) | ((u32)bfbits(b) << 16);
}

static __device__ __forceinline__ float exp2_fast(float x) {
  float r;
  asm("v_exp_f32 %0, %1" : "=v"(r) : "v"(x));
  return r;
}

// HW transpose read: lane l receives column (l&15) of the 4x16 bf16 tile.
static __device__ __forceinline__ bf16x4 tr16(u32 byte_addr) {
  bf16x4 d;
  asm volatile("ds_read_b64_tr_b16 %0, %1" : "=v"(d) : "v"(byte_addr));
  return d;
}

#define MFMA16(A, B, C) __builtin_amdgcn_mfma_f32_16x16x32_bf16(A, B, C, 0, 0, 0)
#define BARRIER asm volatile("s_barrier" ::: "memory")

// ======== fused prep: cvt(x) + transpose(Wqkv) + transpose(Wout) ========
// One dispatch (12288 blocks): small transpose tasks backfill the cvt tail.
__global__ __launch_bounds__(256) void k_prep(const float* __restrict__ x,
                                              u16* __restrict__ xb,
                                              const float* __restrict__ Wq,
                                              u16* __restrict__ wqt,
                                              const float* __restrict__ Wo,
                                              u16* __restrict__ wot) {
  __shared__ float tile[32][33];
  const int bid = blockIdx.x, tid = threadIdx.x;
  if (bid < 8192) {
    int i = bid * 256 + tid;   // < 2097152 exactly
    float4 v = reinterpret_cast<const float4*>(x)[i];
    u16x4 o = { f2bf(v.x), f2bf(v.y), f2bf(v.z), f2bf(v.w) };
    *reinterpret_cast<u16x4*>(xb + (size_t)i * 4) = o;
    return;
  }
  const float* in;
  u16* out;
  int bx, by, C;
  if (bid < 8192 + 3072) {
    int t = bid - 8192;
    in = Wq; out = wqt; C = 3 * DIM;
    bx = (t % 96) * 32; by = (t / 96) * 32;
  } else {
    int t = bid - 11264;
    in = Wo; out = wot; C = DIM;
    bx = (t & 31) * 32; by = (t >> 5) * 32;
  }
  const int R = DIM;
  int tx = tid & 31, ty = tid >> 5;   // ty: 0..7
  #pragma unroll
  for (int i = 0; i < 32; i += 8)
    tile[ty + i][tx] = in[(size_t)(by + ty + i) * C + bx + tx];
  __syncthreads();
  #pragma unroll
  for (int i = 0; i < 32; i += 8)
    out[(size_t)(bx + ty + i) * R + by + tx] = f2bf(tile[tx][ty + i]);
}

// ======== 256x128 single-barrier GEMM, BK=32, triple-buffer (R15 exact) ========
// Best-of-six GEMM1 config: 64.0us, MfmaUtil 35%, 0 conflicts.
// 8 waves (4M x 2N, per-wave 64x64), 512 thr. A ring 3x16KB + B ring 3x8KB
// = 72KB -> 2 blocks/CU. One barrier per K-tile; counted vmcnt(3); stage(t+2)
// after ds_reads. Swizzle byte^=((byte>>9)&1)<<5.
template <int OUT_BF16>
__global__ __launch_bounds__(512, 2) void k_gemm8p(const u16* __restrict__ A,
                                                   const u16* __restrict__ Bt,
                                                   const float* __restrict__ bias,
                                                   u16* __restrict__ Cb,
                                                   float* __restrict__ Cf,
                                                   int M, int N, int K,
                                                   int scale_cols, float scale,
                                                   int nbx) {
  __shared__ __align__(16) char lds[73728];   // A: 3*16KB at 0, B: 3*8KB at 49152

  const int tid = threadIdx.x;
  const int nwg = gridDim.x;
  const int qq = nwg >> 3, rm = nwg & 7;
  const int xcd = blockIdx.x & 7, lidx = blockIdx.x >> 3;
  const int swz = (xcd < rm ? xcd * (qq + 1) : rm * (qq + 1) + (xcd - rm) * qq) + lidx;
  const int m0 = (swz / nbx) * 256, n0 = (swz % nbx) * 128;

  const int w = tid >> 6, lane = tid & 63;
  const int g = lane >> 4, r = lane & 15;
  const int wm = w >> 1, wn = w & 1;   // 4 M-waves x 2 N-waves

  f32x4 acc[4][4] = {};
  const int KT = K >> 5;   // 32

  auto stageA = [&](int t) {
    char* base = lds + (t % 3) * 16384;
    #pragma unroll
    for (int i = 0; i < 2; ++i) {
      int o = (tid + i * 512) * 16;
      int l = o ^ (((o >> 9) & 1) << 5);
      int row = l >> 6, kb = l & 63;
      const u16* gp = A + (size_t)(m0 + row) * K + t * 32 + (kb >> 1);
      __builtin_amdgcn_global_load_lds((const AS1 void*)gp, (AS3 void*)(base + o), 16, 0, 0);
    }
  };
  auto stageB = [&](int t) {
    char* base = lds + 49152 + (t % 3) * 8192;
    int o = tid * 16;
    int l = o ^ (((o >> 9) & 1) << 5);
    int row = l >> 6, kb = l & 63;
    const u16* gp = Bt + (size_t)(n0 + row) * K + t * 32 + (kb >> 1);
    __builtin_amdgcn_global_load_lds((const AS1 void*)gp, (AS3 void*)(base + o), 16, 0, 0);
  };
  auto ldAf = [&](int t, int f) -> bf16x8 {
    const char* base = lds + (t % 3) * 16384;
    int l = (wm * 64 + f * 16 + r) * 64 + g * 16;
    return *(const bf16x8*)(base + (l ^ (((l >> 9) & 1) << 5)));
  };
  auto ldBf = [&](int t, int c) -> bf16x8 {
    const char* base = lds + 49152 + (t % 3) * 8192;
    int l = (wn * 64 + c * 16 + r) * 64 + g * 16;
    return *(const bf16x8*)(base + (l ^ (((l >> 9) & 1) << 5)));
  };

  stageA(0); stageB(0); stageA(1); stageB(1);
  asm volatile("s_waitcnt vmcnt(3)" ::: "memory");
  BARRIER;

  for (int t = 0; t < KT; ++t) {
    const bool st = (t + 2 < KT);
    bf16x8 a0 = ldAf(t, 0), a1 = ldAf(t, 1), a2 = ldAf(t, 2), a3 = ldAf(t, 3);
    bf16x8 b0 = ldBf(t, 0), b1 = ldBf(t, 1), b2 = ldBf(t, 2), b3 = ldBf(t, 3);
    if (st) { stageA(t + 2); stageB(t + 2); }
    __builtin_amdgcn_s_setprio(1);
    acc[0][0] = MFMA16(a0, b0, acc[0][0]);
    acc[0][1] = MFMA16(a0, b1, acc[0][1]);
    acc[0][2] = MFMA16(a0, b2, acc[0][2]);
    acc[0][3] = MFMA16(a0, b3, acc[0][3]);
    acc[1][0] = MFMA16(a1, b0, acc[1][0]);
    acc[1][1] = MFMA16(a1, b1, acc[1][1]);
    acc[1][2] = MFMA16(a1, b2, acc[1][2]);
    acc[1][3] = MFMA16(a1, b3, acc[1][3]);
    acc[2][0] = MFMA16(a2, b0, acc[2][0]);
    acc[2][1] = MFMA16(a2, b1, acc[2][1]);
    acc[2][2] = MFMA16(a2, b2, acc[2][2]);
    acc[2][3] = MFMA16(a2, b3, acc[2][3]);
    acc[3][0] = MFMA16(a3, b0, acc[3][0]);
    acc[3][1] = MFMA16(a3, b1, acc[3][1]);
    acc[3][2] = MFMA16(a3, b2, acc[3][2]);
    acc[3][3] = MFMA16(a3, b3, acc[3][3]);
    __builtin_amdgcn_s_setprio(0);
    if (st) asm volatile("s_waitcnt vmcnt(3)" ::: "memory");
    else    asm volatile("s_waitcnt vmcnt(0)" ::: "memory");
    BARRIER;
  }

  #pragma unroll
  for (int c = 0; c < 4; ++c) {
    int col = n0 + wn * 64 + c * 16 + r;
    float bv = bias[col];
    float sc = (col < scale_cols) ? scale : 1.0f;
    #pragma unroll
    for (int f = 0; f < 4; ++f) {
      #pragma unroll
      for (int e = 0; e < 4; ++e) {
        int row = m0 + wm * 64 + f * 16 + g * 4 + e;
        float val = (acc[f][c][e] + bv) * sc;
        if (OUT_BF16) Cb[(size_t)row * N + col] = f2bf(val);
        else          Cf[(size_t)row * N + col] = val;
      }
    }
  }
}

// ======== 128x128 single-barrier GEMM (R10/R18-proven) — GEMM2 geometry ====
template <int OUT_BF16>
__global__ __launch_bounds__(256, 3) void k_gemm128(const u16* __restrict__ A,
                                                    const u16* __restrict__ Bt,
                                                    const float* __restrict__ bias,
                                                    u16* __restrict__ Cb,
                                                    float* __restrict__ Cf,
                                                    int M, int N, int K,
                                                    int scale_cols, float scale,
                                                    int nbx) {
  __shared__ __align__(16) char lds[49152];   // A: 3*8KB at 0, B: 3*8KB at 24576

  const int tid = threadIdx.x;
  const int nwg = gridDim.x;
  const int qq = nwg >> 3, rm = nwg & 7;
  const int xcd = blockIdx.x & 7, lidx = blockIdx.x >> 3;
  const int swz = (xcd < rm ? xcd * (qq + 1) : rm * (qq + 1) + (xcd - rm) * qq) + lidx;
  const int m0 = (swz / nbx) * 128, n0 = (swz % nbx) * 128;

  const int w = tid >> 6, lane = tid & 63;
  const int g = lane >> 4, r = lane & 15;
  const int wm = w >> 1, wn = w & 1;

  f32x4 acc[4][4] = {};
  const int KT = K >> 5;

  auto stageT = [&](char* base, const u16* src, int grow0, int kt) {
    #pragma unroll
    for (int i = 0; i < 2; ++i) {
      int o = (tid + i * 256) * 16;
      int l = o ^ (((o >> 9) & 1) << 5);
      int row = l >> 6, kb = l & 63;
      const u16* gp = src + (size_t)(grow0 + row) * K + kt * 32 + (kb >> 1);
      __builtin_amdgcn_global_load_lds((const AS1 void*)gp, (AS3 void*)(base + o), 16, 0, 0);
    }
  };
  auto stageA = [&](int t) { stageT(lds + (t % 3) * 8192, A, m0, t); };
  auto stageB = [&](int t) { stageT(lds + 24576 + (t % 3) * 8192, Bt, n0, t); };

  auto ldAf = [&](int t, int f) -> bf16x8 {
    const char* base = lds + (t % 3) * 8192;
    int l = (wm * 64 + f * 16 + r) * 64 + g * 16;
    return *(const bf16x8*)(base + (l ^ (((l >> 9) & 1) << 5)));
  };
  auto ldBf = [&](int t, int c) -> bf16x8 {
    const char* base = lds + 24576 + (t % 3) * 8192;
    int l = (wn * 64 + c * 16 + r) * 64 + g * 16;
    return *(const bf16x8*)(base + (l ^ (((l >> 9) & 1) << 5)));
  };

  stageA(0); stageB(0); stageA(1); stageB(1);
  asm volatile("s_waitcnt vmcnt(4)" ::: "memory");
  BARRIER;

  for (int t = 0; t < KT; ++t) {
    const bool st = (t + 2 < KT);
    bf16x8 a0 = ldAf(t, 0), a1 = ldAf(t, 1), a2 = ldAf(t, 2), a3 = ldAf(t, 3);
    bf16x8 b0 = ldBf(t, 0), b1 = ldBf(t, 1), b2 = ldBf(t, 2), b3 = ldBf(t, 3);
    if (st) { stageA(t + 2); stageB(t + 2); }
    __builtin_amdgcn_s_setprio(1);
    acc[0][0] = MFMA16(a0, b0, acc[0][0]);
    acc[0][1] = MFMA16(a0, b1, acc[0][1]);
    acc[0][2] = MFMA16(a0, b2, acc[0][2]);
    acc[0][3] = MFMA16(a0, b3, acc[0][3]);
    acc[1][0] = MFMA16(a1, b0, acc[1][0]);
    acc[1][1] = MFMA16(a1, b1, acc[1][1]);
    acc[1][2] = MFMA16(a1, b2, acc[1][2]);
    acc[1][3] = MFMA16(a1, b3, acc[1][3]);
    acc[2][0] = MFMA16(a2, b0, acc[2][0]);
    acc[2][1] = MFMA16(a2, b1, acc[2][1]);
    acc[2][2] = MFMA16(a2, b2, acc[2][2]);
    acc[2][3] = MFMA16(a2, b3, acc[2][3]);
    acc[3][0] = MFMA16(a3, b0, acc[3][0]);
    acc[3][1] = MFMA16(a3, b1, acc[3][1]);
    acc[3][2] = MFMA16(a3, b2, acc[3][2]);
    acc[3][3] = MFMA16(a3, b3, acc[3][3]);
    __builtin_amdgcn_s_setprio(0);
    if (st) asm volatile("s_waitcnt vmcnt(4)" ::: "memory");
    else    asm volatile("s_waitcnt vmcnt(0)" ::: "memory");
    BARRIER;
  }

  #pragma unroll
  for (int c = 0; c < 4; ++c) {
    int col = n0 + wn * 64 + c * 16 + r;
    float bv = bias[col];
    float sc = (col < scale_cols) ? scale : 1.0f;
    #pragma unroll
    for (int f = 0; f < 4; ++f) {
      #pragma unroll
      for (int e = 0; e < 4; ++e) {
        int row = m0 + wm * 64 + f * 16 + g * 4 + e;
        float val = (acc[f][c][e] + bv) * sc;
        if (OUT_BF16) Cb[(size_t)row * N + col] = f2bf(val);
        else          Cf[(size_t)row * N + col] = val;
      }
    }
  }
}

// ---------------- causal flash attention (R19: un-paired, KVB=64) ----------------
#define KVB 64
#define LBUF16 8192   // u16 per buffer: K 4096 + V 4096

__global__ __launch_bounds__(256, 2) void k_attn(const u16* __restrict__ qkv,
                                                 u16* __restrict__ aout) {
  __shared__ __align__(16) u16 smem[2 * LBUF16];   // 32 KB

  const int bid = blockIdx.x;
  const int xcd = bid & 7, lidx = bid >> 3;        // 1024 blocks
  const int bh = xcd * 8 + (lidx & 7);             // same-bh -> same XCD
  const int qt = 15 - (lidx >> 3);                 // qt=15 blocks dispatch first
  const int b = bh >> 4, h = bh & 15;
  const int tid = threadIdx.x, w = tid >> 6, lane = tid & 63;
  const int g = lane >> 4, r = lane & 15;

  const int krow0 = tid >> 3;                      // 0..31
  const int kcol = ((tid & 7) ^ (krow0 & 7)) * 8;  // u16 within row
  const int vkey0 = (tid >> 1) & 63;
  const int vcol = (((tid >> 7) << 1) | (tid & 1)) * 8;
  const u16* gQ = qkv + (size_t)(b * TT) * (3 * DIM) + h * HD;
  const u16* kthr = gQ + DIM + (size_t)krow0 * (3 * DIM) + kcol;
  const u16* vthr = gQ + 2 * DIM + (size_t)vkey0 * (3 * DIM) + vcol;

  const u32 lds_base = (u32)(uintptr_t)(AS3 u16*)smem;

  auto issueKV = [&](int buf, int t) {
    u16* kb = &smem[buf * LBUF16];
    u16* vb = &smem[buf * LBUF16 + 4096];
    const size_t toff = (size_t)t * (KVB * 3 * DIM);
    const u16* kt = kthr + toff;
    const u16* vt = vthr + toff;
    #pragma unroll
    for (int i = 0; i < 2; ++i)   // K rows krow0 + 32i
      __builtin_amdgcn_global_load_lds(
          (const AS1 void*)(kt + (size_t)i * 32 * 3 * DIM),
          (AS3 void*)(kb + tid * 8 + i * 2048), 16, 0, 0);
    #pragma unroll
    for (int i = 0; i < 2; ++i)   // V: key vkey0, d cols vcol + 32i
      __builtin_amdgcn_global_load_lds(
          (const AS1 void*)(vt + i * 32),
          (AS3 void*)(vb + tid * 8 + i * 2048), 16, 0, 0);
  };

  const int nt = 2 * qt + 2;               // 64-key tiles
  const int qg0 = qt * 128 + w * 16 + r;   // qb0 row; qb1 = +64

  bf16x8 qf[2][2];
  #pragma unroll
  for (int qb = 0; qb < 2; ++qb) {
    const u16* qp = gQ + (size_t)(qg0 + qb * 64) * (3 * DIM);
    #pragma unroll
    for (int kk = 0; kk < 2; ++kk)
      qf[qb][kk] = *(const bf16x8*)&qp[kk * 32 + g * 8];
  }

  f32x4 o[2][4] = {};
  float lrow[2] = { 0.f, 0.f };

  issueKV(0, 0);
  issueKV(1, 1);   // nt >= 2 always
  __syncthreads();

  for (int t = 0; t < nt; ++t) {
    const bool skip0 = (t == nt - 1);   // qb0 fully masked on last tile
    const bool m0 = (t == nt - 2);
    const bool m1 = (t == nt - 1);
    const int k0 = t * KVB;
    const u16* lk = &smem[(t & 1) * LBUF16];
    const u32 vbyte = lds_base + (t & 1) * (LBUF16 * 2) + 4096 * 2;
    const int sw = (r & 7) << 3;

    bf16x8 kf[4][2];
    #pragma unroll
    for (int c = 0; c < 4; ++c) {
      const int row = c * 16 + r;
      kf[c][0] = *(const bf16x8*)&lk[(row * 64 + g * 8) ^ sw];
      kf[c][1] = *(const bf16x8*)&lk[(row * 64 + 32 + g * 8) ^ sw];
    }
    f32x4 s0[4] = {}, s1[4] = {};
    __builtin_amdgcn_s_setprio(1);
    #pragma unroll
    for (int c = 0; c < 4; ++c) {
      if (!skip0) {
        s0[c] = MFMA16(kf[c][0], qf[0][0], s0[c]);
        s0[c] = MFMA16(kf[c][1], qf[0][1], s0[c]);
      }
      s1[c] = MFMA16(kf[c][0], qf[1][0], s1[c]);
      s1[c] = MFMA16(kf[c][1], qf[1][1], s1[c]);
    }
    __builtin_amdgcn_s_setprio(0);

    bf16x4 tr[4][4];
    const u32 vs = vbyte + (u32)lane * 8;
    #pragma unroll
    for (int cd = 0; cd < 4; ++cd)
      #pragma unroll
      for (int kh = 0; kh < 4; ++kh)
        tr[cd][kh] = tr16(vs + cd * 2048 + kh * 512);

    bf16x8 pf0[2], pf1[2];
    auto softmax = [&](f32x4* s, float& lref, bf16x8* pf, bool msk, int qg) {
      float pv[16];
      #pragma unroll
      for (int c = 0; c < 4; ++c)
        #pragma unroll
        for (int e = 0; e < 4; ++e)
          pv[c * 4 + e] = s[c][e];
      if (msk) {
        #pragma unroll
        for (int c = 0; c < 4; ++c)
          #pragma unroll
          for (int e = 0; e < 4; ++e)
            if (k0 + c * 16 + g * 4 + e > qg) pv[c * 4 + e] = NEG_INF;
      }
      #pragma unroll
      for (int i = 0; i < 16; ++i) pv[i] = exp2_fast(pv[i]);  // exp2(-inf)=0
      float a8[8];
      #pragma unroll
      for (int i = 0; i < 8; ++i) a8[i] = pv[i] + pv[i + 8];
      #pragma unroll
      for (int i = 0; i < 4; ++i) a8[i] = a8[i] + a8[i + 4];
      lref += (a8[0] + a8[1]) + (a8[2] + a8[3]);   // per-lane partial
      union { bf16x8 v; u32 wd[4]; } u0, u1;
      #pragma unroll
      for (int k = 0; k < 4; ++k) {
        u0.wd[k] = pk_bf16(pv[2 * k], pv[2 * k + 1]);
        u1.wd[k] = pk_bf16(pv[8 + 2 * k], pv[9 + 2 * k]);
      }
      pf[0] = u0.v; pf[1] = u1.v;
    };
    if (!skip0) softmax(s0, lrow[0], pf0, m0, qg0);
    softmax(s1, lrow[1], pf1, m1, qg0 + 64);

    asm volatile("s_waitcnt lgkmcnt(0)" ::: "memory");
    __builtin_amdgcn_sched_barrier(0);
    __builtin_amdgcn_s_setprio(1);
    #pragma unroll
    for (int cd = 0; cd < 4; ++cd) {
      #pragma unroll
      for (int ks = 0; ks < 2; ++ks) {
        bf16x4 lo = tr[cd][ks * 2], hi = tr[cd][ks * 2 + 1];
        bf16x8 av = { lo[0], lo[1], lo[2], lo[3], hi[0], hi[1], hi[2], hi[3] };
        if (!skip0) o[0][cd] = MFMA16(av, pf0[ks], o[0][cd]);
        o[1][cd] = MFMA16(av, pf1[ks], o[1][cd]);
      }
    }
    __builtin_amdgcn_s_setprio(0);

    __syncthreads();
    if (t + 2 < nt) issueKV(t & 1, t + 2);
  }

  #pragma unroll
  for (int qb = 0; qb < 2; ++qb) {
    float l = lrow[qb];
    l += __shfl_xor(l, 16);
    l += __shfl_xor(l, 32);
    const float inv = 1.0f / l;
    u16* op = aout + (size_t)(b * TT + qg0 + qb * 64) * DIM + h * HD;
    #pragma unroll
    for (int cd = 0; cd < 4; ++cd) {
      union { u16x4 v; u32 wd[2]; } pk;
      pk.wd[0] = pk_bf16(o[qb][cd][0] * inv, o[qb][cd][1] * inv);
      pk.wd[1] = pk_bf16(o[qb][cd][2] * inv, o[qb][cd][3] * inv);
      *(u16x4*)&op[cd * 16 + g * 4] = pk.v;
    }
  }
}

// ---------------- launcher ----------------
extern "C" void kernel_launch(void* const* d_in, const int* in_sizes, int n_in,
                              void* d_out, int out_size, void* d_ws, size_t ws_size,
                              hipStream_t stream) {
  const float* x    = (const float*)d_in[0];
  const float* Wqkv = (const float*)d_in[1];
  const float* bqkv = (const float*)d_in[2];
  const float* Wout = (const float*)d_in[3];
  const float* bout = (const float*)d_in[4];
  float* out = (float*)d_out;

  const int M = BB * TT;  // 8192
  u16* xb   = (u16*)d_ws;                      // [8192][1024]
  u16* wqt  = xb + (size_t)M * DIM;            // [3072][1024]
  u16* wot  = wqt + (size_t)3 * DIM * DIM;     // [1024][1024]
  u16* qkvb = wot + (size_t)DIM * DIM;         // [8192][3072]
  u16* aob  = qkvb + (size_t)M * 3 * DIM;      // [8192][1024]

  // fused conversions: cvt(x) + Wqkv^T + Wout^T in one dispatch
  k_prep<<<8192 + 3072 + 1024, 256, 0, stream>>>(x, xb, Wqkv, wqt, Wout, wot);

  // qkv = x @ W_qkv + b_qkv  (bf16 out; Q cols pre-scaled) — R15 best GEMM1
  k_gemm8p<1><<<(M / 256) * (3 * DIM / 128), 512, 0, stream>>>(
      xb, wqt, bqkv, qkvb, nullptr, M, 3 * DIM, DIM, DIM, QSCALE, 3 * DIM / 128);

  // attention — R19 un-paired: 64 bh x 16 qt = 1024 blocks
  k_attn<<<BB * NH * 16, 256, 0, stream>>>(qkvb, aob);

  // out = attn_out @ W_out + b_out  (f32 out) — R18 geometry
  k_gemm128<0><<<(M / 128) * (DIM / 128), 256, 0, stream>>>(
      aob, wot, bout, nullptr, out, M, DIM, DIM, 0, 1.0f, DIM / 128);
}

// Round 24
// 147.683 us; speedup vs baseline: 1.0016x; 1.0016x over previous
//
#include <hip/hip_runtime.h>
#include <hip/hip_bf16.h>
#include <cstdint>
#include <cstddef>

#define DIM   1024
#define NH    16
#define HD    64
#define BB    4
#define TT    2048

typedef __attribute__((ext_vector_type(8))) short bf16x8;
typedef __attribute__((ext_vector_type(4))) short bf16x4;
typedef __attribute__((ext_vector_type(4))) float f32x4;
typedef __attribute__((ext_vector_type(4))) unsigned short u16x4;
typedef unsigned short u16;
typedef unsigned int u32;

#define NEG_INF (-__builtin_inff())
#define QSCALE 0.18033688011110543f  // 0.125 * log2(e): softmax becomes exp2
#define AS1 __attribute__((address_space(1)))
#define AS3 __attribute__((address_space(3)))

static __device__ __forceinline__ u16 f2bf(float f) {
  union { float f; unsigned u; } v; v.f = f;
  return (u16)((v.u + 0x7FFFu + ((v.u >> 16) & 1u)) >> 16);
}

static __device__ __forceinline__ u16 bfbits(float a) {
  union { __hip_bfloat16 h; u16 u; } c; c.h = __float2bfloat16(a); return c.u;
}
static __device__ __forceinline__ u32 pk_bf16(float a, float b) {
  return (u32)bfbits(a) | ((u32)bfbits(b) << 16);
}

static __device__ __forceinline__ float exp2_fast(float x) {
  float r;
  asm("v_exp_f32 %0, %1" : "=v"(r) : "v"(x));
  return r;
}

// HW transpose read: lane l receives column (l&15) of the 4x16 bf16 tile.
static __device__ __forceinline__ bf16x4 tr16(u32 byte_addr) {
  bf16x4 d;
  asm volatile("ds_read_b64_tr_b16 %0, %1" : "=v"(d) : "v"(byte_addr));
  return d;
}

#define MFMA16(A, B, C) __builtin_amdgcn_mfma_f32_16x16x32_bf16(A, B, C, 0, 0, 0)
#define BARRIER asm volatile("s_barrier" ::: "memory")

// ======== fused prep: cvt(x) + transpose(Wqkv) + transpose(Wout) ========
// One dispatch (12288 blocks): small transpose tasks backfill the cvt tail.
__global__ __launch_bounds__(256) void k_prep(const float* __restrict__ x,
                                              u16* __restrict__ xb,
                                              const float* __restrict__ Wq,
                                              u16* __restrict__ wqt,
                                              const float* __restrict__ Wo,
                                              u16* __restrict__ wot) {
  __shared__ float tile[32][33];
  const int bid = blockIdx.x, tid = threadIdx.x;
  if (bid < 8192) {
    int i = bid * 256 + tid;   // < 2097152 exactly
    float4 v = reinterpret_cast<const float4*>(x)[i];
    u16x4 o = { f2bf(v.x), f2bf(v.y), f2bf(v.z), f2bf(v.w) };
    *reinterpret_cast<u16x4*>(xb + (size_t)i * 4) = o;
    return;
  }
  const float* in;
  u16* out;
  int bx, by, C;
  if (bid < 8192 + 3072) {
    int t = bid - 8192;
    in = Wq; out = wqt; C = 3 * DIM;
    bx = (t % 96) * 32; by = (t / 96) * 32;
  } else {
    int t = bid - 11264;
    in = Wo; out = wot; C = DIM;
    bx = (t & 31) * 32; by = (t >> 5) * 32;
  }
  const int R = DIM;
  int tx = tid & 31, ty = tid >> 5;   // ty: 0..7
  #pragma unroll
  for (int i = 0; i < 32; i += 8)
    tile[ty + i][tx] = in[(size_t)(by + ty + i) * C + bx + tx];
  __syncthreads();
  #pragma unroll
  for (int i = 0; i < 32; i += 8)
    out[(size_t)(bx + ty + i) * R + by + tx] = f2bf(tile[tx][ty + i]);
}

// ======== 256x128 single-barrier GEMM, BK=32, triple-buffer (R15 exact) ========
// Best-of-six GEMM1 config: 64.0us, MfmaUtil 35%, 0 conflicts.
// 8 waves (4M x 2N, per-wave 64x64), 512 thr. A ring 3x16KB + B ring 3x8KB
// = 72KB -> 2 blocks/CU. One barrier per K-tile; counted vmcnt(3); stage(t+2)
// after ds_reads. Swizzle byte^=((byte>>9)&1)<<5.
template <int OUT_BF16>
__global__ __launch_bounds__(512, 2) void k_gemm8p(const u16* __restrict__ A,
                                                   const u16* __restrict__ Bt,
                                                   const float* __restrict__ bias,
                                                   u16* __restrict__ Cb,
                                                   float* __restrict__ Cf,
                                                   int M, int N, int K,
                                                   int scale_cols, float scale,
                                                   int nbx) {
  __shared__ __align__(16) char lds[73728];   // A: 3*16KB at 0, B: 3*8KB at 49152

  const int tid = threadIdx.x;
  const int nwg = gridDim.x;
  const int qq = nwg >> 3, rm = nwg & 7;
  const int xcd = blockIdx.x & 7, lidx = blockIdx.x >> 3;
  const int swz = (xcd < rm ? xcd * (qq + 1) : rm * (qq + 1) + (xcd - rm) * qq) + lidx;
  const int m0 = (swz / nbx) * 256, n0 = (swz % nbx) * 128;

  const int w = tid >> 6, lane = tid & 63;
  const int g = lane >> 4, r = lane & 15;
  const int wm = w >> 1, wn = w & 1;   // 4 M-waves x 2 N-waves

  f32x4 acc[4][4] = {};
  const int KT = K >> 5;   // 32

  auto stageA = [&](int t) {
    char* base = lds + (t % 3) * 16384;
    #pragma unroll
    for (int i = 0; i < 2; ++i) {
      int o = (tid + i * 512) * 16;
      int l = o ^ (((o >> 9) & 1) << 5);
      int row = l >> 6, kb = l & 63;
      const u16* gp = A + (size_t)(m0 + row) * K + t * 32 + (kb >> 1);
      __builtin_amdgcn_global_load_lds((const AS1 void*)gp, (AS3 void*)(base + o), 16, 0, 0);
    }
  };
  auto stageB = [&](int t) {
    char* base = lds + 49152 + (t % 3) * 8192;
    int o = tid * 16;
    int l = o ^ (((o >> 9) & 1) << 5);
    int row = l >> 6, kb = l & 63;
    const u16* gp = Bt + (size_t)(n0 + row) * K + t * 32 + (kb >> 1);
    __builtin_amdgcn_global_load_lds((const AS1 void*)gp, (AS3 void*)(base + o), 16, 0, 0);
  };
  auto ldAf = [&](int t, int f) -> bf16x8 {
    const char* base = lds + (t % 3) * 16384;
    int l = (wm * 64 + f * 16 + r) * 64 + g * 16;
    return *(const bf16x8*)(base + (l ^ (((l >> 9) & 1) << 5)));
  };
  auto ldBf = [&](int t, int c) -> bf16x8 {
    const char* base = lds + 49152 + (t % 3) * 8192;
    int l = (wn * 64 + c * 16 + r) * 64 + g * 16;
    return *(const bf16x8*)(base + (l ^ (((l >> 9) & 1) << 5)));
  };

  stageA(0); stageB(0); stageA(1); stageB(1);
  asm volatile("s_waitcnt vmcnt(3)" ::: "memory");
  BARRIER;

  for (int t = 0; t < KT; ++t) {
    const bool st = (t + 2 < KT);
    bf16x8 a0 = ldAf(t, 0), a1 = ldAf(t, 1), a2 = ldAf(t, 2), a3 = ldAf(t, 3);
    bf16x8 b0 = ldBf(t, 0), b1 = ldBf(t, 1), b2 = ldBf(t, 2), b3 = ldBf(t, 3);
    if (st) { stageA(t + 2); stageB(t + 2); }
    __builtin_amdgcn_s_setprio(1);
    acc[0][0] = MFMA16(a0, b0, acc[0][0]);
    acc[0][1] = MFMA16(a0, b1, acc[0][1]);
    acc[0][2] = MFMA16(a0, b2, acc[0][2]);
    acc[0][3] = MFMA16(a0, b3, acc[0][3]);
    acc[1][0] = MFMA16(a1, b0, acc[1][0]);
    acc[1][1] = MFMA16(a1, b1, acc[1][1]);
    acc[1][2] = MFMA16(a1, b2, acc[1][2]);
    acc[1][3] = MFMA16(a1, b3, acc[1][3]);
    acc[2][0] = MFMA16(a2, b0, acc[2][0]);
    acc[2][1] = MFMA16(a2, b1, acc[2][1]);
    acc[2][2] = MFMA16(a2, b2, acc[2][2]);
    acc[2][3] = MFMA16(a2, b3, acc[2][3]);
    acc[3][0] = MFMA16(a3, b0, acc[3][0]);
    acc[3][1] = MFMA16(a3, b1, acc[3][1]);
    acc[3][2] = MFMA16(a3, b2, acc[3][2]);
    acc[3][3] = MFMA16(a3, b3, acc[3][3]);
    __builtin_amdgcn_s_setprio(0);
    if (st) asm volatile("s_waitcnt vmcnt(3)" ::: "memory");
    else    asm volatile("s_waitcnt vmcnt(0)" ::: "memory");
    BARRIER;
  }

  #pragma unroll
  for (int c = 0; c < 4; ++c) {
    int col = n0 + wn * 64 + c * 16 + r;
    float bv = bias[col];
    float sc = (col < scale_cols) ? scale : 1.0f;
    #pragma unroll
    for (int f = 0; f < 4; ++f) {
      #pragma unroll
      for (int e = 0; e < 4; ++e) {
        int row = m0 + wm * 64 + f * 16 + g * 4 + e;
        float val = (acc[f][c][e] + bv) * sc;
        if (OUT_BF16) Cb[(size_t)row * N + col] = f2bf(val);
        else          Cf[(size_t)row * N + col] = val;
      }
    }
  }
}

// ======== 128x128 single-barrier GEMM (R10/R18-proven) — GEMM2 geometry ====
template <int OUT_BF16>
__global__ __launch_bounds__(256, 3) void k_gemm128(const u16* __restrict__ A,
                                                    const u16* __restrict__ Bt,
                                                    const float* __restrict__ bias,
                                                    u16* __restrict__ Cb,
                                                    float* __restrict__ Cf,
                                                    int M, int N, int K,
                                                    int scale_cols, float scale,
                                                    int nbx) {
  __shared__ __align__(16) char lds[49152];   // A: 3*8KB at 0, B: 3*8KB at 24576

  const int tid = threadIdx.x;
  const int nwg = gridDim.x;
  const int qq = nwg >> 3, rm = nwg & 7;
  const int xcd = blockIdx.x & 7, lidx = blockIdx.x >> 3;
  const int swz = (xcd < rm ? xcd * (qq + 1) : rm * (qq + 1) + (xcd - rm) * qq) + lidx;
  const int m0 = (swz / nbx) * 128, n0 = (swz % nbx) * 128;

  const int w = tid >> 6, lane = tid & 63;
  const int g = lane >> 4, r = lane & 15;
  const int wm = w >> 1, wn = w & 1;

  f32x4 acc[4][4] = {};
  const int KT = K >> 5;

  auto stageT = [&](char* base, const u16* src, int grow0, int kt) {
    #pragma unroll
    for (int i = 0; i < 2; ++i) {
      int o = (tid + i * 256) * 16;
      int l = o ^ (((o >> 9) & 1) << 5);
      int row = l >> 6, kb = l & 63;
      const u16* gp = src + (size_t)(grow0 + row) * K + kt * 32 + (kb >> 1);
      __builtin_amdgcn_global_load_lds((const AS1 void*)gp, (AS3 void*)(base + o), 16, 0, 0);
    }
  };
  auto stageA = [&](int t) { stageT(lds + (t % 3) * 8192, A, m0, t); };
  auto stageB = [&](int t) { stageT(lds + 24576 + (t % 3) * 8192, Bt, n0, t); };

  auto ldAf = [&](int t, int f) -> bf16x8 {
    const char* base = lds + (t % 3) * 8192;
    int l = (wm * 64 + f * 16 + r) * 64 + g * 16;
    return *(const bf16x8*)(base + (l ^ (((l >> 9) & 1) << 5)));
  };
  auto ldBf = [&](int t, int c) -> bf16x8 {
    const char* base = lds + 24576 + (t % 3) * 8192;
    int l = (wn * 64 + c * 16 + r) * 64 + g * 16;
    return *(const bf16x8*)(base + (l ^ (((l >> 9) & 1) << 5)));
  };

  stageA(0); stageB(0); stageA(1); stageB(1);
  asm volatile("s_waitcnt vmcnt(4)" ::: "memory");
  BARRIER;

  for (int t = 0; t < KT; ++t) {
    const bool st = (t + 2 < KT);
    bf16x8 a0 = ldAf(t, 0), a1 = ldAf(t, 1), a2 = ldAf(t, 2), a3 = ldAf(t, 3);
    bf16x8 b0 = ldBf(t, 0), b1 = ldBf(t, 1), b2 = ldBf(t, 2), b3 = ldBf(t, 3);
    if (st) { stageA(t + 2); stageB(t + 2); }
    __builtin_amdgcn_s_setprio(1);
    acc[0][0] = MFMA16(a0, b0, acc[0][0]);
    acc[0][1] = MFMA16(a0, b1, acc[0][1]);
    acc[0][2] = MFMA16(a0, b2, acc[0][2]);
    acc[0][3] = MFMA16(a0, b3, acc[0][3]);
    acc[1][0] = MFMA16(a1, b0, acc[1][0]);
    acc[1][1] = MFMA16(a1, b1, acc[1][1]);
    acc[1][2] = MFMA16(a1, b2, acc[1][2]);
    acc[1][3] = MFMA16(a1, b3, acc[1][3]);
    acc[2][0] = MFMA16(a2, b0, acc[2][0]);
    acc[2][1] = MFMA16(a2, b1, acc[2][1]);
    acc[2][2] = MFMA16(a2, b2, acc[2][2]);
    acc[2][3] = MFMA16(a2, b3, acc[2][3]);
    acc[3][0] = MFMA16(a3, b0, acc[3][0]);
    acc[3][1] = MFMA16(a3, b1, acc[3][1]);
    acc[3][2] = MFMA16(a3, b2, acc[3][2]);
    acc[3][3] = MFMA16(a3, b3, acc[3][3]);
    __builtin_amdgcn_s_setprio(0);
    if (st) asm volatile("s_waitcnt vmcnt(4)" ::: "memory");
    else    asm volatile("s_waitcnt vmcnt(0)" ::: "memory");
    BARRIER;
  }

  #pragma unroll
  for (int c = 0; c < 4; ++c) {
    int col = n0 + wn * 64 + c * 16 + r;
    float bv = bias[col];
    float sc = (col < scale_cols) ? scale : 1.0f;
    #pragma unroll
    for (int f = 0; f < 4; ++f) {
      #pragma unroll
      for (int e = 0; e < 4; ++e) {
        int row = m0 + wm * 64 + f * 16 + g * 4 + e;
        float val = (acc[f][c][e] + bv) * sc;
        if (OUT_BF16) Cb[(size_t)row * N + col] = f2bf(val);
        else          Cf[(size_t)row * N + col] = val;
      }
    }
  }
}

// ---------------- causal flash attention (R19: un-paired, KVB=64) ----------------
#define KVB 64
#define LBUF16 8192   // u16 per buffer: K 4096 + V 4096

__global__ __launch_bounds__(256, 2) void k_attn(const u16* __restrict__ qkv,
                                                 u16* __restrict__ aout) {
  __shared__ __align__(16) u16 smem[2 * LBUF16];   // 32 KB

  const int bid = blockIdx.x;
  const int xcd = bid & 7, lidx = bid >> 3;        // 1024 blocks
  const int bh = xcd * 8 + (lidx & 7);             // same-bh -> same XCD
  const int qt = 15 - (lidx >> 3);                 // qt=15 blocks dispatch first
  const int b = bh >> 4, h = bh & 15;
  const int tid = threadIdx.x, w = tid >> 6, lane = tid & 63;
  const int g = lane >> 4, r = lane & 15;

  const int krow0 = tid >> 3;                      // 0..31
  const int kcol = ((tid & 7) ^ (krow0 & 7)) * 8;  // u16 within row
  const int vkey0 = (tid >> 1) & 63;
  const int vcol = (((tid >> 7) << 1) | (tid & 1)) * 8;
  const u16* gQ = qkv + (size_t)(b * TT) * (3 * DIM) + h * HD;
  const u16* kthr = gQ + DIM + (size_t)krow0 * (3 * DIM) + kcol;
  const u16* vthr = gQ + 2 * DIM + (size_t)vkey0 * (3 * DIM) + vcol;

  const u32 lds_base = (u32)(uintptr_t)(AS3 u16*)smem;

  auto issueKV = [&](int buf, int t) {
    u16* kb = &smem[buf * LBUF16];
    u16* vb = &smem[buf * LBUF16 + 4096];
    const size_t toff = (size_t)t * (KVB * 3 * DIM);
    const u16* kt = kthr + toff;
    const u16* vt = vthr + toff;
    #pragma unroll
    for (int i = 0; i < 2; ++i)   // K rows krow0 + 32i
      __builtin_amdgcn_global_load_lds(
          (const AS1 void*)(kt + (size_t)i * 32 * 3 * DIM),
          (AS3 void*)(kb + tid * 8 + i * 2048), 16, 0, 0);
    #pragma unroll
    for (int i = 0; i < 2; ++i)   // V: key vkey0, d cols vcol + 32i
      __builtin_amdgcn_global_load_lds(
          (const AS1 void*)(vt + i * 32),
          (AS3 void*)(vb + tid * 8 + i * 2048), 16, 0, 0);
  };

  const int nt = 2 * qt + 2;               // 64-key tiles
  const int qg0 = qt * 128 + w * 16 + r;   // qb0 row; qb1 = +64

  bf16x8 qf[2][2];
  #pragma unroll
  for (int qb = 0; qb < 2; ++qb) {
    const u16* qp = gQ + (size_t)(qg0 + qb * 64) * (3 * DIM);
    #pragma unroll
    for (int kk = 0; kk < 2; ++kk)
      qf[qb][kk] = *(const bf16x8*)&qp[kk * 32 + g * 8];
  }

  f32x4 o[2][4] = {};
  float lrow[2] = { 0.f, 0.f };

  issueKV(0, 0);
  issueKV(1, 1);   // nt >= 2 always
  __syncthreads();

  for (int t = 0; t < nt; ++t) {
    const bool skip0 = (t == nt - 1);   // qb0 fully masked on last tile
    const bool m0 = (t == nt - 2);
    const bool m1 = (t == nt - 1);
    const int k0 = t * KVB;
    const u16* lk = &smem[(t & 1) * LBUF16];
    const u32 vbyte = lds_base + (t & 1) * (LBUF16 * 2) + 4096 * 2;
    const int sw = (r & 7) << 3;

    bf16x8 kf[4][2];
    #pragma unroll
    for (int c = 0; c < 4; ++c) {
      const int row = c * 16 + r;
      kf[c][0] = *(const bf16x8*)&lk[(row * 64 + g * 8) ^ sw];
      kf[c][1] = *(const bf16x8*)&lk[(row * 64 + 32 + g * 8) ^ sw];
    }
    f32x4 s0[4] = {}, s1[4] = {};
    __builtin_amdgcn_s_setprio(1);
    #pragma unroll
    for (int c = 0; c < 4; ++c) {
      if (!skip0) {
        s0[c] = MFMA16(kf[c][0], qf[0][0], s0[c]);
        s0[c] = MFMA16(kf[c][1], qf[0][1], s0[c]);
      }
      s1[c] = MFMA16(kf[c][0], qf[1][0], s1[c]);
      s1[c] = MFMA16(kf[c][1], qf[1][1], s1[c]);
    }
    __builtin_amdgcn_s_setprio(0);

    bf16x4 tr[4][4];
    const u32 vs = vbyte + (u32)lane * 8;
    #pragma unroll
    for (int cd = 0; cd < 4; ++cd)
      #pragma unroll
      for (int kh = 0; kh < 4; ++kh)
        tr[cd][kh] = tr16(vs + cd * 2048 + kh * 512);

    bf16x8 pf0[2], pf1[2];
    auto softmax = [&](f32x4* s, float& lref, bf16x8* pf, bool msk, int qg) {
      float pv[16];
      #pragma unroll
      for (int c = 0; c < 4; ++c)
        #pragma unroll
        for (int e = 0; e < 4; ++e)
          pv[c * 4 + e] = s[c][e];
      if (msk) {
        #pragma unroll
        for (int c = 0; c < 4; ++c)
          #pragma unroll
          for (int e = 0; e < 4; ++e)
            if (k0 + c * 16 + g * 4 + e > qg) pv[c * 4 + e] = NEG_INF;
      }
      #pragma unroll
      for (int i = 0; i < 16; ++i) pv[i] = exp2_fast(pv[i]);  // exp2(-inf)=0
      float a8[8];
      #pragma unroll
      for (int i = 0; i < 8; ++i) a8[i] = pv[i] + pv[i + 8];
      #pragma unroll
      for (int i = 0; i < 4; ++i) a8[i] = a8[i] + a8[i + 4];
      lref += (a8[0] + a8[1]) + (a8[2] + a8[3]);   // per-lane partial
      union { bf16x8 v; u32 wd[4]; } u0, u1;
      #pragma unroll
      for (int k = 0; k < 4; ++k) {
        u0.wd[k] = pk_bf16(pv[2 * k], pv[2 * k + 1]);
        u1.wd[k] = pk_bf16(pv[8 + 2 * k], pv[9 + 2 * k]);
      }
      pf[0] = u0.v; pf[1] = u1.v;
    };
    if (!skip0) softmax(s0, lrow[0], pf0, m0, qg0);
    softmax(s1, lrow[1], pf1, m1, qg0 + 64);

    asm volatile("s_waitcnt lgkmcnt(0)" ::: "memory");
    __builtin_amdgcn_sched_barrier(0);
    __builtin_amdgcn_s_setprio(1);
    #pragma unroll
    for (int cd = 0; cd < 4; ++cd) {
      #pragma unroll
      for (int ks = 0; ks < 2; ++ks) {
        bf16x4 lo = tr[cd][ks * 2], hi = tr[cd][ks * 2 + 1];
        bf16x8 av = { lo[0], lo[1], lo[2], lo[3], hi[0], hi[1], hi[2], hi[3] };
        if (!skip0) o[0][cd] = MFMA16(av, pf0[ks], o[0][cd]);
        o[1][cd] = MFMA16(av, pf1[ks], o[1][cd]);
      }
    }
    __builtin_amdgcn_s_setprio(0);

    __syncthreads();
    if (t + 2 < nt) issueKV(t & 1, t + 2);
  }

  #pragma unroll
  for (int qb = 0; qb < 2; ++qb) {
    float l = lrow[qb];
    l += __shfl_xor(l, 16);
    l += __shfl_xor(l, 32);
    const float inv = 1.0f / l;
    u16* op = aout + (size_t)(b * TT + qg0 + qb * 64) * DIM + h * HD;
    #pragma unroll
    for (int cd = 0; cd < 4; ++cd) {
      union { u16x4 v; u32 wd[2]; } pk;
      pk.wd[0] = pk_bf16(o[qb][cd][0] * inv, o[qb][cd][1] * inv);
      pk.wd[1] = pk_bf16(o[qb][cd][2] * inv, o[qb][cd][3] * inv);
      *(u16x4*)&op[cd * 16 + g * 4] = pk.v;
    }
  }
}

// ---------------- launcher ----------------
extern "C" void kernel_launch(void* const* d_in, const int* in_sizes, int n_in,
                              void* d_out, int out_size, void* d_ws, size_t ws_size,
                              hipStream_t stream) {
  const float* x    = (const float*)d_in[0];
  const float* Wqkv = (const float*)d_in[1];
  const float* bqkv = (const float*)d_in[2];
  const float* Wout = (const float*)d_in[3];
  const float* bout = (const float*)d_in[4];
  float* out = (float*)d_out;

  const int M = BB * TT;  // 8192
  u16* xb   = (u16*)d_ws;                      // [8192][1024]
  u16* wqt  = xb + (size_t)M * DIM;            // [3072][1024]
  u16* wot  = wqt + (size_t)3 * DIM * DIM;     // [1024][1024]
  u16* qkvb = wot + (size_t)DIM * DIM;         // [8192][3072]
  u16* aob  = qkvb + (size_t)M * 3 * DIM;      // [8192][1024]

  // fused conversions: cvt(x) + Wqkv^T + Wout^T in one dispatch
  k_prep<<<8192 + 3072 + 1024, 256, 0, stream>>>(x, xb, Wqkv, wqt, Wout, wot);

  // qkv = x @ W_qkv + b_qkv  (bf16 out; Q cols pre-scaled) — R15 best GEMM1
  k_gemm8p<1><<<(M / 256) * (3 * DIM / 128), 512, 0, stream>>>(
      xb, wqt, bqkv, qkvb, nullptr, M, 3 * DIM, DIM, DIM, QSCALE, 3 * DIM / 128);

  // attention — R19 un-paired: 64 bh x 16 qt = 1024 blocks
  k_attn<<<BB * NH * 16, 256, 0, stream>>>(qkvb, aob);

  // out = attn_out @ W_out + b_out  (f32 out) — R18 geometry
  k_gemm128<0><<<(M / 128) * (DIM / 128), 256, 0, stream>>>(
      aob, wot, bout, nullptr, out, M, DIM, DIM, 0, 1.0f, DIM / 128);
}